// Round 5
// baseline (232.551 us; speedup 1.0000x reference)
//
#include <hip/hip_runtime.h>
#include <hip/hip_cooperative_groups.h>

namespace cg = cooperative_groups;

#define NP      4096
#define NQ      32768
#define KNN     32
#define RADIUS  0.1f
#define R2      (RADIUS * RADIUS)
#define NCELLS  1000          // 10x10x10 grid, cell edge = RADIUS
#define CAP_P   24            // max particles/cell  (lambda=4.1,  +10 sigma)
#define CAP_Q   96            // max queries/cell    (lambda=32.8, +11 sigma)
#define NBR_CAP 704           // >= 27*CAP_P = 648

// ws layout (bytes):
//   +0       int    pCount[1000]   \ zeroed in phase 0 (8192 B = 2048 ints)
//   +4096    int    qCount[1000]   /
//   +8192    ushort qIdx[1000*96]
//   +200704  float4 pBucket[1000*24]    -> total 584704 B
#define WS_NEEDED 584704u

// ---------------- Fused cooperative kernel: zero -> bin -> per-cell ----------------
__global__ __launch_bounds__(128) void fused_kernel(
    const float* __restrict__ rp, const float* __restrict__ pc,
    int* __restrict__ pCount, int* __restrict__ qCount,
    unsigned short* __restrict__ qIdx, float4* __restrict__ pBucket,
    float* __restrict__ out)
{
    cg::grid_group grid = cg::this_grid();

    const int tid = threadIdx.x;
    const int gt  = blockIdx.x * 128 + tid;   // 1000*128 = 128000 threads

    // ---- phase 0: zero the two count arrays (2048 ints, contiguous at ws+0) ----
    if (gt < 2048) pCount[gt] = 0;
    grid.sync();

    // ---- phase 1: bin particles + queries (one item per thread) ----
    if (gt < NP) {
        int i = gt;
        float x = pc[3*i], y = pc[3*i+1], z = pc[3*i+2];
        int cx = min(max((int)(x * 10.f), 0), 9);
        int cy = min(max((int)(y * 10.f), 0), 9);
        int cz = min(max((int)(z * 10.f), 0), 9);
        int c  = (cx * 10 + cy) * 10 + cz;
        int pos = atomicAdd(&pCount[c], 1);
        if (pos < CAP_P) pBucket[c * CAP_P + pos] = make_float4(x, y, z, __int_as_float(i));
    } else if (gt - NP < NQ) {
        int i = gt - NP;
        float x = rp[3*i], y = rp[3*i+1], z = rp[3*i+2];
        int cx = min(max((int)(x * 10.f), 0), 9);
        int cy = min(max((int)(y * 10.f), 0), 9);
        int cz = min(max((int)(z * 10.f), 0), 9);
        int c  = (cx * 10 + cy) * 10 + cz;
        int pos = atomicAdd(&qCount[c], 1);
        if (pos < CAP_Q) qIdx[c * CAP_Q + pos] = (unsigned short)i;
    }
    __threadfence();
    grid.sync();

    // ---- phase 2: per-cell processing (identical to validated cell_kernel) ----
    __shared__ float4 nbr[NBR_CAP];
    __shared__ float  sd2[NBR_CAP];
    __shared__ int    counts[27], ncell[27], offs[28];
    __shared__ int    nrare;
    __shared__ unsigned short rlist[CAP_Q];
    __shared__ float  ord[KNN][4];

    const int c  = blockIdx.x;
    const int cz = c % 10, cy = (c / 10) % 10, cx = c / 100;

    if (tid < 27) {
        int dx = tid / 9 - 1, dy = (tid / 3) % 3 - 1, dz = tid % 3 - 1;
        int nx = cx + dx, ny = cy + dy, nz = cz + dz;
        bool valid = (unsigned)nx < 10u && (unsigned)ny < 10u && (unsigned)nz < 10u;
        int nc = valid ? (nx * 10 + ny) * 10 + nz : 0;
        ncell[tid]  = nc;
        counts[tid] = valid ? min(pCount[nc], CAP_P) : 0;
    }
    if (tid == 0) nrare = 0;
    __syncthreads();
    if (tid == 0) {
        int s = 0;
        for (int i = 0; i < 27; ++i) { offs[i] = s; s += counts[i]; }
        offs[27] = s;
    }
    __syncthreads();
    const int M = offs[27];

    if (tid < 108) {
        int ci = tid >> 2, sub = tid & 3;
        int cnt = counts[ci], base = offs[ci], nc = ncell[ci];
        for (int e = sub; e < cnt; e += 4)
            nbr[base + e] = pBucket[nc * CAP_P + e];
    }
    __syncthreads();

    // fast path: 4 threads per query, LDS broadcast reads
    const int nq = min(qCount[c], CAP_Q);
    const int sub = tid & 3;
    for (int i = tid >> 2; i < nq; i += 32) {
        const int qi = qIdx[c * CAP_Q + i];
        const float qx = rp[3*qi], qy = rp[3*qi+1], qz = rp[3*qi+2];
        float sw = 0.f, swx = 0.f, swy = 0.f, swz = 0.f;
        int cnt = 0;
        for (int j = sub; j < M; j += 4) {
            float4 pp = nbr[j];
            float dx = pp.x - qx, dy = pp.y - qy, dz = pp.z - qz;
            float d2 = fmaf(dx, dx, fmaf(dy, dy, dz * dz));
            float d  = sqrtf(d2);
            float w  = fmaxf(fmaf(d2 * d, -1000.f, 1.f), 0.f);  // 1-(d/R)^3, 0 outside
            sw  += w;
            swx = fmaf(w, pp.x, swx);
            swy = fmaf(w, pp.y, swy);
            swz = fmaf(w, pp.z, swz);
            cnt += (d2 <= R2) ? 1 : 0;
        }
        #pragma unroll
        for (int m = 1; m <= 2; m <<= 1) {
            sw  += __shfl_xor(sw,  m);
            swx += __shfl_xor(swx, m);
            swy += __shfl_xor(swy, m);
            swz += __shfl_xor(swz, m);
            cnt += __shfl_xor(cnt, m);
        }
        if (sub == 0) {
            if (cnt <= KNN) {
                // masked slots gather particle 0 then zero -> nn_d = ||q||
                float nq2 = fmaf(qx, qx, fmaf(qy, qy, qz * qz));
                float nqd = sqrtf(nq2);
                float w0  = fmaxf(fmaf(nq2 * nqd, -1000.f, 1.f), 0.f);
                float dens = sw + (float)(KNN - cnt) * w0;
                float inv  = 1.f / (dens + 1e-12f);
                ((float4*)out)[qi] = make_float4(swx * inv, swy * inv, swz * inv, dens);
            } else {
                int pos = atomicAdd(&nrare, 1);
                rlist[pos] = (unsigned short)qi;
            }
        }
    }
    __syncthreads();

    // rare path (cnt > K): exact top-K by (d2, idx) lexicographic rank
    for (int r = 0; r < nrare; ++r) {
        const int qi = rlist[r];
        const float qx = rp[3*qi], qy = rp[3*qi+1], qz = rp[3*qi+2];
        for (int j = tid; j < M; j += 128) {
            float4 pp = nbr[j];
            float dx = pp.x - qx, dy = pp.y - qy, dz = pp.z - qz;
            sd2[j] = fmaf(dx, dx, fmaf(dy, dy, dz * dz));
        }
        __syncthreads();
        for (int j = tid; j < M; j += 128) {
            float dj = sd2[j];
            if (dj <= R2) {
                int ij = __float_as_int(nbr[j].w);
                int rank = 0;
                for (int k = 0; k < M; ++k) {
                    float dk = sd2[k];
                    int   ik = __float_as_int(nbr[k].w);
                    rank += (dk < dj || (dk == dj && ik < ij)) ? 1 : 0;
                }
                if (rank < KNN) {
                    float4 pp = nbr[j];
                    float d = sqrtf(dj);
                    float w = fmaxf(fmaf(dj * d, -1000.f, 1.f), 0.f);
                    ord[rank][0] = w;
                    ord[rank][1] = w * pp.x;
                    ord[rank][2] = w * pp.y;
                    ord[rank][3] = w * pp.z;
                }
            }
        }
        __syncthreads();
        if (tid == 0) {
            float t0 = 0.f, t1 = 0.f, t2 = 0.f, t3 = 0.f;
            #pragma unroll
            for (int k = 0; k < KNN; ++k) {
                t0 += ord[k][0]; t1 += ord[k][1]; t2 += ord[k][2]; t3 += ord[k][3];
            }
            float inv = 1.f / (t0 + 1e-12f);    // cnt>K: m=0, no masked slots
            ((float4*)out)[qi] = make_float4(t1 * inv, t2 * inv, t3 * inv, t0);
        }
        __syncthreads();
    }
}

// ---------------- Fallback (validated round-1 monolithic) if ws too small ----------------
#define BLKQ   64
#define NWAVE  8
#define CHUNK  (NP / NWAVE)
#define THREADS (BLKQ * NWAVE)

__global__ __launch_bounds__(THREADS) void knn_smooth_kernel(
    const float* __restrict__ rp, const float* __restrict__ pc, float* __restrict__ out)
{
    __shared__ float4 sp[NP];
    __shared__ float  red[5][NWAVE][BLKQ];
    __shared__ int    sflag[BLKQ];
    __shared__ int    scnt;
    __shared__ float  ord[KNN][4];

    const int tid = threadIdx.x, lane = tid & 63, wv = tid >> 6, blk = blockIdx.x;
    float* spf = (float*)sp;
    for (int i = tid; i < NP * 3; i += THREADS) {
        int p = i / 3, ccc = i - 3 * p;
        spf[4 * p + ccc] = pc[i];
    }
    __syncthreads();
    const int q = blk * BLKQ + lane;
    const float qx = rp[3*q], qy = rp[3*q+1], qz = rp[3*q+2];
    float sw = 0.f, swx = 0.f, swy = 0.f, swz = 0.f; int cnt = 0;
    const int p0 = wv * CHUNK;
    #pragma unroll 4
    for (int p = p0; p < p0 + CHUNK; ++p) {
        float4 pp = sp[p];
        float dx = pp.x - qx, dy = pp.y - qy, dz = pp.z - qz;
        float d2 = fmaf(dx, dx, fmaf(dy, dy, dz * dz));
        if (d2 <= R2) {
            float d = sqrtf(d2);
            float w = fmaxf(fmaf(d2 * d, -1000.f, 1.f), 0.f);
            cnt += 1; sw += w;
            swx = fmaf(w, pp.x, swx); swy = fmaf(w, pp.y, swy); swz = fmaf(w, pp.z, swz);
        }
    }
    red[0][wv][lane] = sw; red[1][wv][lane] = swx; red[2][wv][lane] = swy;
    red[3][wv][lane] = swz; red[4][wv][lane] = (float)cnt;
    __syncthreads();
    if (tid < BLKQ) {
        float tsw = 0.f, tswx = 0.f, tswy = 0.f, tswz = 0.f; int tc = 0;
        #pragma unroll
        for (int w = 0; w < NWAVE; ++w) {
            tsw += red[0][w][tid]; tswx += red[1][w][tid]; tswy += red[2][w][tid];
            tswz += red[3][w][tid]; tc += (int)red[4][w][tid];
        }
        int flagged = (tc > KNN) ? 1 : 0;
        sflag[tid] = flagged;
        if (!flagged) {
            float nq2 = fmaf(qx, qx, fmaf(qy, qy, qz * qz));
            float nqd = sqrtf(nq2);
            float w0 = fmaxf(fmaf(nq2 * nqd, -1000.f, 1.f), 0.f);
            float dens = tsw + (float)(KNN - tc) * w0;
            float inv = 1.f / (dens + 1e-12f);
            ((float4*)out)[q] = make_float4(tswx * inv, tswy * inv, tswz * inv, dens);
        }
    }
    __syncthreads();
    float* sd2 = &red[0][0][0];
    int*   sid = (int*)(sd2 + 1024);
    for (int f = 0; f < BLKQ; ++f) {
        if (!sflag[f]) continue;
        if (tid == 0) scnt = 0;
        __syncthreads();
        const int fq = blk * BLKQ + f;
        const float fx = rp[3*fq], fy = rp[3*fq+1], fz = rp[3*fq+2];
        for (int p = tid; p < NP; p += THREADS) {
            float4 pp = sp[p];
            float dx = pp.x - fx, dy = pp.y - fy, dz = pp.z - fz;
            float d2 = fmaf(dx, dx, fmaf(dy, dy, dz * dz));
            if (d2 <= R2) {
                int pos = atomicAdd(&scnt, 1);
                if (pos < 1024) { sd2[pos] = d2; sid[pos] = p; }
            }
        }
        __syncthreads();
        const int ne = (scnt < 1024) ? scnt : 1024;
        for (int e = tid; e < ne; e += THREADS) {
            float myd = sd2[e]; int myi = sid[e]; int rank = 0;
            for (int j = 0; j < ne; ++j) {
                float dj = sd2[j]; int ij = sid[j];
                rank += (dj < myd || (dj == myd && ij < myi)) ? 1 : 0;
            }
            if (rank < KNN) {
                float4 pp = sp[myi];
                float d = sqrtf(myd);
                float w = fmaxf(fmaf(myd * d, -1000.f, 1.f), 0.f);
                ord[rank][0] = w; ord[rank][1] = w * pp.x;
                ord[rank][2] = w * pp.y; ord[rank][3] = w * pp.z;
            }
        }
        __syncthreads();
        if (tid == 0) {
            float t0 = 0.f, t1 = 0.f, t2 = 0.f, t3 = 0.f;
            #pragma unroll
            for (int k = 0; k < KNN; ++k) {
                t0 += ord[k][0]; t1 += ord[k][1]; t2 += ord[k][2]; t3 += ord[k][3];
            }
            float inv = 1.f / (t0 + 1e-12f);
            ((float4*)out)[fq] = make_float4(t1 * inv, t2 * inv, t3 * inv, t0);
        }
        __syncthreads();
    }
}

extern "C" void kernel_launch(void* const* d_in, const int* in_sizes, int n_in,
                              void* d_out, int out_size, void* d_ws, size_t ws_size,
                              hipStream_t stream) {
    const float* rp  = (const float*)d_in[0];   // [512,64,3]
    const float* pc  = (const float*)d_in[1];   // [4096,3]
    float*       out = (float*)d_out;           // [512,64,4]

    if (ws_size < WS_NEEDED) {
        knn_smooth_kernel<<<NQ / BLKQ, THREADS, 0, stream>>>(rp, pc, out);
        return;
    }

    int*            pCount  = (int*)d_ws;                             // +0
    int*            qCount  = (int*)((char*)d_ws + 4096);             // +4096
    unsigned short* qIdx    = (unsigned short*)((char*)d_ws + 8192);  // +8192
    float4*         pBucket = (float4*)((char*)d_ws + 200704);        // +200704

    void* args[] = { (void*)&rp, (void*)&pc, (void*)&pCount, (void*)&qCount,
                     (void*)&qIdx, (void*)&pBucket, (void*)&out };
    hipLaunchCooperativeKernel((const void*)fused_kernel, dim3(NCELLS), dim3(128),
                               args, 0, stream);
}

// Round 6
// 37.419 us; speedup vs baseline: 6.2148x; 6.2148x over previous
//
#include <hip/hip_runtime.h>

#define NP      4096
#define NQ      32768
#define KNN     32
#define RADIUS  0.1f
#define R2      (RADIUS * RADIUS)
#define NCELLS  1000          // 10x10x10 grid, cell edge = RADIUS
#define CAP_P   24            // max particles/cell (lambda=4.1, P(>24) ~ 1e-11)
#define NBR_CAP 704           // >= 27*CAP_P = 648
#define QPB     128           // queries per block
#define TPB     512           // threads per block (4 sub-threads per query)

// Single self-sufficient kernel: each block stages ALL particles into an LDS
// spatial hash, then answers its 128 queries from LDS only. No workspace,
// no inter-kernel dependencies, no grid sync.
__global__ __launch_bounds__(TPB, 1) void fused1(
    const float* __restrict__ rp,   // [NQ,3]
    const float* __restrict__ pc,   // [NP,3]
    float* __restrict__ out)        // [NQ,4]
{
    __shared__ float4          sp[NP];              // 64 KB particle positions
    __shared__ unsigned short  bkt[NCELLS][CAP_P];  // 48 KB cell -> particle idx
    __shared__ int             bcnt[NCELLS];        //  4 KB cell counts
    __shared__ float           rd2[NBR_CAP];        // rare-path d2 table
    __shared__ unsigned short  rid[NBR_CAP];        // rare-path particle idx
    __shared__ unsigned short  rlist[QPB];          // rare query list
    __shared__ float           ord[KNN][4];         // rank-ordered accumulation
    __shared__ int             nrare, rn;

    const int tid = threadIdx.x;

    // ---- phase 0: zero cell counts ----
    for (int i = tid; i < NCELLS; i += TPB) bcnt[i] = 0;
    if (tid == 0) nrare = 0;
    __syncthreads();

    // ---- phase 1: stage + bin all particles into LDS hash ----
    for (int i = tid; i < NP; i += TPB) {
        float x = pc[3*i], y = pc[3*i+1], z = pc[3*i+2];
        sp[i] = make_float4(x, y, z, 0.f);
        int cx = min(max((int)(x * 10.f), 0), 9);
        int cy = min(max((int)(y * 10.f), 0), 9);
        int cz = min(max((int)(z * 10.f), 0), 9);
        int c  = (cx * 10 + cy) * 10 + cz;
        int pos = atomicAdd(&bcnt[c], 1);
        if (pos < CAP_P) bkt[c][pos] = (unsigned short)i;
    }
    __syncthreads();

    // ---- phase 2: fast path — 4 sub-threads per query walk 27 cells ----
    const int sub = tid & 3;
    const int qi  = blockIdx.x * QPB + (tid >> 2);
    const float qx = rp[3*qi], qy = rp[3*qi+1], qz = rp[3*qi+2];
    const int cx = min(max((int)(qx * 10.f), 0), 9);
    const int cy = min(max((int)(qy * 10.f), 0), 9);
    const int cz = min(max((int)(qz * 10.f), 0), 9);

    float sw = 0.f, swx = 0.f, swy = 0.f, swz = 0.f;
    int cnt = 0;
    for (int ci = sub; ci < 27; ci += 4) {
        int nx = cx + ci / 9 - 1;
        int ny = cy + (ci / 3) % 3 - 1;
        int nz = cz + ci % 3 - 1;
        if ((unsigned)nx >= 10u || (unsigned)ny >= 10u || (unsigned)nz >= 10u) continue;
        int cc = (nx * 10 + ny) * 10 + nz;
        int n  = min(bcnt[cc], CAP_P);
        for (int e = 0; e < n; ++e) {
            float4 pp = sp[bkt[cc][e]];
            float dx = pp.x - qx, dy = pp.y - qy, dz = pp.z - qz;
            float d2 = fmaf(dx, dx, fmaf(dy, dy, dz * dz));
            float d  = sqrtf(d2);
            float w  = fmaxf(fmaf(d2 * d, -1000.f, 1.f), 0.f);  // 1-(d/R)^3, 0 outside
            sw  += w;
            swx = fmaf(w, pp.x, swx);
            swy = fmaf(w, pp.y, swy);
            swz = fmaf(w, pp.z, swz);
            cnt += (d2 <= R2) ? 1 : 0;
        }
    }
    #pragma unroll
    for (int m = 1; m <= 2; m <<= 1) {
        sw  += __shfl_xor(sw,  m);
        swx += __shfl_xor(swx, m);
        swy += __shfl_xor(swy, m);
        swz += __shfl_xor(swz, m);
        cnt += __shfl_xor(cnt, m);
    }
    if (sub == 0) {
        if (cnt <= KNN) {
            // masked slots gather particle 0 then get zeroed -> nn_d = ||q||
            float nq2 = fmaf(qx, qx, fmaf(qy, qy, qz * qz));
            float nqd = sqrtf(nq2);
            float w0  = fmaxf(fmaf(nq2 * nqd, -1000.f, 1.f), 0.f);
            float dens = sw + (float)(KNN - cnt) * w0;
            float inv  = 1.f / (dens + 1e-12f);
            ((float4*)out)[qi] = make_float4(swx * inv, swy * inv, swz * inv, dens);
        } else {
            int pos = atomicAdd(&nrare, 1);
            rlist[pos] = (unsigned short)(qi - blockIdx.x * QPB);
        }
    }
    __syncthreads();

    // ---- phase 3: rare path (cnt > K) — exact top-K by (d2, idx) rank ----
    for (int r = 0; r < nrare; ++r) {             // block-uniform, ~0.06 per block
        const int fq = blockIdx.x * QPB + rlist[r];
        const float fx = rp[3*fq], fy = rp[3*fq+1], fz = rp[3*fq+2];
        const int fcx = min(max((int)(fx * 10.f), 0), 9);
        const int fcy = min(max((int)(fy * 10.f), 0), 9);
        const int fcz = min(max((int)(fz * 10.f), 0), 9);
        if (tid == 0) rn = 0;
        __syncthreads();
        // gather all 27-cell candidates with their d2
        for (int t = tid; t < 27 * CAP_P; t += TPB) {
            int ci = t / CAP_P, e = t % CAP_P;
            int nx = fcx + ci / 9 - 1;
            int ny = fcy + (ci / 3) % 3 - 1;
            int nz = fcz + ci % 3 - 1;
            if ((unsigned)nx >= 10u || (unsigned)ny >= 10u || (unsigned)nz >= 10u) continue;
            int cc = (nx * 10 + ny) * 10 + nz;
            if (e >= min(bcnt[cc], CAP_P)) continue;
            int p = bkt[cc][e];
            float4 pp = sp[p];
            float dx = pp.x - fx, dy = pp.y - fy, dz = pp.z - fz;
            float d2 = fmaf(dx, dx, fmaf(dy, dy, dz * dz));
            int pos = atomicAdd(&rn, 1);
            rd2[pos] = d2;
            rid[pos] = (unsigned short)p;
        }
        __syncthreads();
        const int ne = rn;
        for (int e = tid; e < ne; e += TPB) {
            float dj = rd2[e];
            if (dj <= R2) {
                int ij = rid[e];
                int rank = 0;
                for (int k = 0; k < ne; ++k) {
                    float dk = rd2[k];
                    int   ik = rid[k];
                    rank += (dk < dj || (dk == dj && ik < ij)) ? 1 : 0;
                }
                if (rank < KNN) {                 // exactly K entries (cnt > K in-ball)
                    float4 pp = sp[ij];
                    float d = sqrtf(dj);
                    float w = fmaxf(fmaf(dj * d, -1000.f, 1.f), 0.f);
                    ord[rank][0] = w;
                    ord[rank][1] = w * pp.x;
                    ord[rank][2] = w * pp.y;
                    ord[rank][3] = w * pp.z;
                }
            }
        }
        __syncthreads();
        if (tid == 0) {
            float t0 = 0.f, t1 = 0.f, t2 = 0.f, t3 = 0.f;
            #pragma unroll
            for (int k = 0; k < KNN; ++k) {
                t0 += ord[k][0]; t1 += ord[k][1]; t2 += ord[k][2]; t3 += ord[k][3];
            }
            float inv = 1.f / (t0 + 1e-12f);      // cnt>K: no masked slots
            ((float4*)out)[fq] = make_float4(t1 * inv, t2 * inv, t3 * inv, t0);
        }
        __syncthreads();
    }
}

extern "C" void kernel_launch(void* const* d_in, const int* in_sizes, int n_in,
                              void* d_out, int out_size, void* d_ws, size_t ws_size,
                              hipStream_t stream) {
    const float* rp  = (const float*)d_in[0];   // ray_particles [512,64,3]
    const float* pc  = (const float*)d_in[1];   // particles    [4096,3]
    float*       out = (float*)d_out;           // [512,64,4]
    fused1<<<NQ / QPB, TPB, 0, stream>>>(rp, pc, out);
}